// Round 24
// baseline (178.495 us; speedup 1.0000x reference)
//
#include <hip/hip_runtime.h>
#include <math.h>

// x: [8, 32, 32, 512] -> rows M = 8192, C = 512, heads = 8, hd = 64
#define M_ROWS   8192
#define CDIM     512
#define QKV_N    1536
#define NTOK     1024
#define HEADS    8
#define HD       64
#define EPS      1e-3f
#define SCALE    0.125f   // 64^-0.5
#define SCL2E    0.18033688011112042f   // SCALE * log2(e)

typedef __attribute__((ext_vector_type(8))) short short8;
typedef __attribute__((ext_vector_type(4))) float f32x4;
typedef unsigned short ushort_t;

// -------------------- helpers --------------------

__device__ __forceinline__ ushort_t f2bf(float f) {
    union { float f; unsigned int u; } v; v.f = f;
    unsigned int r = v.u + 0x7fffu + ((v.u >> 16) & 1u);   // RNE
    return (ushort_t)(r >> 16);
}
__device__ __forceinline__ float bf2f(ushort_t u) {
    union { unsigned int u; float f; } v; v.u = ((unsigned int)u) << 16;
    return v.f;
}

// async global->LDS 16B copy: per-lane global src, wave-uniform LDS base
// (HW adds lane*16). Drained by the vmcnt(0) the compiler emits at barriers.
__device__ __forceinline__ void stage16(const void* g, void* l) {
    __builtin_amdgcn_global_load_lds(
        (__attribute__((address_space(1))) void*)(g),
        (__attribute__((address_space(3))) void*)(l), 16, 0, 0);
}

__device__ __forceinline__ void get_alpha(const float* __restrict__ fw,
                                          float& a0, float& a1)
{
    const float m  = fmaxf(fw[0], fw[1]);
    const float e0 = __expf(fw[0] - m);
    const float e1 = __expf(fw[1] - m);
    const float inv = 1.0f / (e0 + e1);
    a0 = e0 * inv;   // sparse
    a1 = e1 * inv;   // dense
}

// -------------------- prep: ln (2048x4 rows) + tconv x4 (512) + bias (1) ----

__device__ __forceinline__ void tconv_body(const float* __restrict__ W,
                                           ushort_t* __restrict__ hiT,
                                           ushort_t* __restrict__ loT,
                                           int N, int ors, int coff,
                                           int bk, int bn, int t,
                                           float (*tile)[65])
{
#pragma unroll
    for (int i = 0; i < 4; ++i) {
        const int idx = t + i * 256;
        const int kl = idx >> 4, nl = (idx & 15) * 4;
        const float4 v = *(const float4*)(W + (size_t)(bk + kl) * N + bn + nl);
        tile[kl][nl] = v.x; tile[kl][nl + 1] = v.y;
        tile[kl][nl + 2] = v.z; tile[kl][nl + 3] = v.w;
    }
    __syncthreads();
#pragma unroll
    for (int i = 0; i < 2; ++i) {
        const int idx = t + i * 256;
        const int nl = idx >> 3, kc = (idx & 7) * 8;
        short8 hv, lv;
#pragma unroll
        for (int j = 0; j < 8; ++j) {
            const float f = tile[kc + j][nl];
            const ushort_t h = f2bf(f);
            hv[j] = (short)h;
            lv[j] = (short)f2bf(f - bf2f(h));
        }
        const size_t ob = (size_t)(bn + nl) * ors + coff + bk + kc;
        *(short8*)(hiT + ob) = hv;
        if (loT) *(short8*)(loT + ob) = lv;
    }
}

__global__ __launch_bounds__(256) void prep_kernel(const float* __restrict__ x,
                                                   const float* __restrict__ gamma,
                                                   const float* __restrict__ beta,
                                                   ushort_t* __restrict__ xhi,
                                                   ushort_t* __restrict__ xlo,
                                                   const float* __restrict__ qkv_d_w,
                                                   ushort_t* __restrict__ WdT_hi,
                                                   const float* __restrict__ qkv_s_w,
                                                   ushort_t* __restrict__ WsT_hi,
                                                   ushort_t* __restrict__ WsT_lo,
                                                   const float* __restrict__ proj_s_w,
                                                   const float* __restrict__ proj_d_w,
                                                   ushort_t* __restrict__ WpT_hi,
                                                   ushort_t* __restrict__ WpT_lo,
                                                   const float* __restrict__ bs,
                                                   const float* __restrict__ bd,
                                                   const float* __restrict__ fw,
                                                   float* __restrict__ biasc)
{
    __shared__ float tile[64][65];
    const int t = threadIdx.x;
    const int blk = blockIdx.x;

    if (blk < 2048) {
        // ---- LayerNorm: one wave per row, wave-local reduce (no barriers) ----
        const int wv   = t >> 6, lane = t & 63;
        const int row  = blk * 4 + wv;
        const float* xr = x + (size_t)row * CDIM + lane * 8;
        const float4 v0 = *(const float4*)(xr);
        const float4 v1 = *(const float4*)(xr + 4);
        float s  = (v0.x + v0.y) + (v0.z + v0.w) + (v1.x + v1.y) + (v1.z + v1.w);
        float ss = (v0.x * v0.x + v0.y * v0.y) + (v0.z * v0.z + v0.w * v0.w)
                 + (v1.x * v1.x + v1.y * v1.y) + (v1.z * v1.z + v1.w * v1.w);
#pragma unroll
        for (int off = 32; off > 0; off >>= 1) {
            s  += __shfl_xor(s,  off, 64);
            ss += __shfl_xor(ss, off, 64);
        }
        const float mu  = s * (1.0f / CDIM);
        const float var = ss * (1.0f / CDIM) - mu * mu;
        const float rs  = rsqrtf(var + EPS);
        const float4 g0 = *(const float4*)(gamma + lane * 8);
        const float4 g1 = *(const float4*)(gamma + lane * 8 + 4);
        const float4 b0 = *(const float4*)(beta + lane * 8);
        const float4 b1 = *(const float4*)(beta + lane * 8 + 4);
        float o[8];
        o[0] = (v0.x - mu) * rs * g0.x + b0.x;
        o[1] = (v0.y - mu) * rs * g0.y + b0.y;
        o[2] = (v0.z - mu) * rs * g0.z + b0.z;
        o[3] = (v0.w - mu) * rs * g0.w + b0.w;
        o[4] = (v1.x - mu) * rs * g1.x + b1.x;
        o[5] = (v1.y - mu) * rs * g1.y + b1.y;
        o[6] = (v1.z - mu) * rs * g1.z + b1.z;
        o[7] = (v1.w - mu) * rs * g1.w + b1.w;
        short8 hv, lv;
#pragma unroll
        for (int j = 0; j < 8; ++j) {
            const ushort_t h = f2bf(o[j]);
            hv[j] = (short)h;
            lv[j] = (short)f2bf(o[j] - bf2f(h));
        }
        *(short8*)(xhi + (size_t)row * CDIM + lane * 8) = hv;
        *(short8*)(xlo + (size_t)row * CDIM + lane * 8) = lv;
        return;
    }
    int idx = blk - 2048;
    if (idx < 192) {
        tconv_body(qkv_d_w, WdT_hi, nullptr, QKV_N, CDIM, 0,
                   (idx & 7) * 64, (idx >> 3) * 64, t, tile);
        return;
    }
    idx -= 192;
    if (idx < 192) {
        tconv_body(qkv_s_w, WsT_hi, WsT_lo, QKV_N, CDIM, 0,
                   (idx & 7) * 64, (idx >> 3) * 64, t, tile);
        return;
    }
    idx -= 192;
    if (idx < 64) {
        tconv_body(proj_s_w, WpT_hi, WpT_lo, CDIM, 1024, 0,
                   (idx & 7) * 64, (idx >> 3) * 64, t, tile);
        return;
    }
    idx -= 64;
    if (idx < 64) {
        tconv_body(proj_d_w, WpT_hi, nullptr, CDIM, 1024, 512,
                   (idx & 7) * 64, (idx >> 3) * 64, t, tile);
        return;
    }
    float a0, a1;
    get_alpha(fw, a0, a1);
    biasc[t]       = a0 * bs[t]       + a1 * bd[t];
    biasc[t + 256] = a0 * bs[t + 256] + a1 * bd[t + 256];
}

// -------------------- bf16 MFMA GEMM: C = A @ B^T + bias --------------------
// MODE 0: plain 1-MFMA. MODE 1: full split (3-MFMA). OUTBF=1: bf16 output to Cb,
// with Q columns (col < 512) pre-scaled by SCL2E so attention skips the
// per-logit scale mul (exact: softmax scale folded into Q).

template<int MODE, int OUTBF>
__global__ __launch_bounds__(256) void gemm_bf16_mfma(const ushort_t* __restrict__ Ahi,
                                                      const ushort_t* __restrict__ Alo,
                                                      const ushort_t* __restrict__ Bhi,
                                                      const ushort_t* __restrict__ Blo,
                                                      const float* __restrict__ bias,
                                                      float* __restrict__ C,
                                                      ushort_t* __restrict__ Cb,
                                                      int N, int K)
{
    const int t  = threadIdx.x;
    const int l  = t & 63, w = t >> 6;
    const int wr = w >> 1, wc = w & 1;
    const int lr = l & 15, lg = l >> 4;
    const int bm = blockIdx.x * 128, bn = blockIdx.y * 128;

    __shared__ ushort_t As[MODE ? 2 : 1][128 * 64];
    __shared__ ushort_t Bs[MODE ? 2 : 1][128 * 64];

    f32x4 acc[4][4];
#pragma unroll
    for (int i = 0; i < 4; ++i)
#pragma unroll
        for (int j = 0; j < 4; ++j) acc[i][j] = (f32x4){0.f, 0.f, 0.f, 0.f};

    const int srow8 = t >> 3;                              // 0..31
    const int sch   = ((t & 7) ^ ((t >> 3) & 7)) * 8;      // pre-swizzled src chunk
    const int lbase = (t >> 6) * 512;                      // wave-uniform LDS base

    for (int kt = 0; kt < K; kt += 64) {
        __syncthreads();
#pragma unroll
        for (int i = 0; i < 4; ++i) {
            const int row = srow8 + i * 32;
            const size_t ga = (size_t)(bm + row) * K + kt + sch;
            const size_t gb = (size_t)(bn + row) * K + kt + sch;
            stage16(Ahi + ga, &As[0][i * 2048 + lbase]);
            stage16(Bhi + gb, &Bs[0][i * 2048 + lbase]);
            if (MODE) {
                stage16(Alo + ga, &As[MODE ? 1 : 0][i * 2048 + lbase]);
                stage16(Blo + gb, &Bs[MODE ? 1 : 0][i * 2048 + lbase]);
            }
        }
        __syncthreads();
#pragma unroll
        for (int ks = 0; ks < 2; ++ks) {
            short8 ah[4], bh[4], al[4], bl[4];
#pragma unroll
            for (int mf = 0; mf < 4; ++mf) {
                const int row = wr * 64 + mf * 16 + lr;
                const int cs  = (((ks * 4 + lg) ^ (row & 7)) * 8);
                ah[mf] = *(const short8*)(&As[0][row * 64 + cs]);
                if (MODE) al[mf] = *(const short8*)(&As[MODE ? 1 : 0][row * 64 + cs]);
            }
#pragma unroll
            for (int nf = 0; nf < 4; ++nf) {
                const int row = wc * 64 + nf * 16 + lr;
                const int cs  = (((ks * 4 + lg) ^ (row & 7)) * 8);
                bh[nf] = *(const short8*)(&Bs[0][row * 64 + cs]);
                if (MODE) bl[nf] = *(const short8*)(&Bs[MODE ? 1 : 0][row * 64 + cs]);
            }
#pragma unroll
            for (int mf = 0; mf < 4; ++mf)
#pragma unroll
                for (int nf = 0; nf < 4; ++nf) {
                    acc[mf][nf] = __builtin_amdgcn_mfma_f32_16x16x32_bf16(ah[mf], bh[nf], acc[mf][nf], 0, 0, 0);
                    if (MODE) {
                        acc[mf][nf] = __builtin_amdgcn_mfma_f32_16x16x32_bf16(al[mf], bh[nf], acc[mf][nf], 0, 0, 0);
                        acc[mf][nf] = __builtin_amdgcn_mfma_f32_16x16x32_bf16(ah[mf], bl[nf], acc[mf][nf], 0, 0, 0);
                    }
                }
        }
    }
    float bv[4];
#pragma unroll
    for (int nf = 0; nf < 4; ++nf) bv[nf] = bias[bn + wc * 64 + nf * 16 + lr];
    const float oscl = (OUTBF && bn < 512) ? SCL2E : 1.0f;   // Q pre-scale
#pragma unroll
    for (int mf = 0; mf < 4; ++mf)
#pragma unroll
        for (int r = 0; r < 4; ++r) {
            const int row = bm + wr * 64 + mf * 16 + lg * 4 + r;
            if (OUTBF) {
                ushort_t* cp = Cb + (size_t)row * N + bn + wc * 64;
#pragma unroll
                for (int nf = 0; nf < 4; ++nf)
                    cp[nf * 16 + lr] = f2bf((acc[mf][nf][r] + bv[nf]) * oscl);
            } else {
                float* cp = C + (size_t)row * N + bn + wc * 64;
#pragma unroll
                for (int nf = 0; nf < 4; ++nf)
                    cp[nf * 16 + lr] = acc[mf][nf][r] + bv[nf];
            }
        }
}

// -------------------- proj GEMM: BM=64 x BN=128, static K-split precision ----

__global__ __launch_bounds__(256) void gemm_proj(const ushort_t* __restrict__ Ahi,
                                                 const ushort_t* __restrict__ Alo,
                                                 const ushort_t* __restrict__ Bhi,
                                                 const ushort_t* __restrict__ Blo,
                                                 const float* __restrict__ bias,
                                                 float* __restrict__ C)
{
    const int t  = threadIdx.x;
    const int l  = t & 63, w = t >> 6;
    const int wr = w >> 1, wc = w & 1;
    const int lr = l & 15, lg = l >> 4;
    const int bm = blockIdx.x * 64, bn = blockIdx.y * 128;

    __shared__ ushort_t As[2][64 * 64];
    __shared__ ushort_t Bs[2][128 * 64];

    f32x4 acc[2][4];
#pragma unroll
    for (int i = 0; i < 2; ++i)
#pragma unroll
        for (int j = 0; j < 4; ++j) acc[i][j] = (f32x4){0.f, 0.f, 0.f, 0.f};

    const int srow8 = t >> 3;                              // 0..31
    const int sch   = ((t & 7) ^ ((t >> 3) & 7)) * 8;
    const int lbase = (t >> 6) * 512;

    // ---- sparse K-half: split precision (3-MFMA) ----
    for (int kt = 0; kt < 512; kt += 64) {
        __syncthreads();
#pragma unroll
        for (int i = 0; i < 2; ++i) {
            const size_t ga = (size_t)(bm + srow8 + i * 32) * 1024 + kt + sch;
            stage16(Ahi + ga, &As[0][i * 2048 + lbase]);
            stage16(Alo + ga, &As[1][i * 2048 + lbase]);
        }
#pragma unroll
        for (int i = 0; i < 4; ++i) {
            const size_t gb = (size_t)(bn + srow8 + i * 32) * 1024 + kt + sch;
            stage16(Bhi + gb, &Bs[0][i * 2048 + lbase]);
            stage16(Blo + gb, &Bs[1][i * 2048 + lbase]);
        }
        __syncthreads();
#pragma unroll
        for (int ks = 0; ks < 2; ++ks) {
            short8 ah[2], al[2], bh[4], bl[4];
#pragma unroll
            for (int mf = 0; mf < 2; ++mf) {
                const int row = wr * 32 + mf * 16 + lr;
                const int cs  = (((ks * 4 + lg) ^ (row & 7)) * 8);
                ah[mf] = *(const short8*)(&As[0][row * 64 + cs]);
                al[mf] = *(const short8*)(&As[1][row * 64 + cs]);
            }
#pragma unroll
            for (int nf = 0; nf < 4; ++nf) {
                const int row = wc * 64 + nf * 16 + lr;
                const int cs  = (((ks * 4 + lg) ^ (row & 7)) * 8);
                bh[nf] = *(const short8*)(&Bs[0][row * 64 + cs]);
                bl[nf] = *(const short8*)(&Bs[1][row * 64 + cs]);
            }
#pragma unroll
            for (int mf = 0; mf < 2; ++mf)
#pragma unroll
                for (int nf = 0; nf < 4; ++nf) {
                    acc[mf][nf] = __builtin_amdgcn_mfma_f32_16x16x32_bf16(ah[mf], bh[nf], acc[mf][nf], 0, 0, 0);
                    acc[mf][nf] = __builtin_amdgcn_mfma_f32_16x16x32_bf16(al[mf], bh[nf], acc[mf][nf], 0, 0, 0);
                    acc[mf][nf] = __builtin_amdgcn_mfma_f32_16x16x32_bf16(ah[mf], bl[nf], acc[mf][nf], 0, 0, 0);
                }
        }
    }

    // ---- dense K-half: plain bf16 (1-MFMA) ----
    for (int kt = 512; kt < 1024; kt += 64) {
        __syncthreads();
#pragma unroll
        for (int i = 0; i < 2; ++i) {
            const size_t ga = (size_t)(bm + srow8 + i * 32) * 1024 + kt + sch;
            stage16(Ahi + ga, &As[0][i * 2048 + lbase]);
        }
#pragma unroll
        for (int i = 0; i < 4; ++i) {
            const size_t gb = (size_t)(bn + srow8 + i * 32) * 1024 + kt + sch;
            stage16(Bhi + gb, &Bs[0][i * 2048 + lbase]);
        }
        __syncthreads();
#pragma unroll
        for (int ks = 0; ks < 2; ++ks) {
            short8 ah[2], bh[4];
#pragma unroll
            for (int mf = 0; mf < 2; ++mf) {
                const int row = wr * 32 + mf * 16 + lr;
                const int cs  = (((ks * 4 + lg) ^ (row & 7)) * 8);
                ah[mf] = *(const short8*)(&As[0][row * 64 + cs]);
            }
#pragma unroll
            for (int nf = 0; nf < 4; ++nf) {
                const int row = wc * 64 + nf * 16 + lr;
                const int cs  = (((ks * 4 + lg) ^ (row & 7)) * 8);
                bh[nf] = *(const short8*)(&Bs[0][row * 64 + cs]);
            }
#pragma unroll
            for (int mf = 0; mf < 2; ++mf)
#pragma unroll
                for (int nf = 0; nf < 4; ++nf)
                    acc[mf][nf] = __builtin_amdgcn_mfma_f32_16x16x32_bf16(ah[mf], bh[nf], acc[mf][nf], 0, 0, 0);
        }
    }

    float bv[4];
#pragma unroll
    for (int nf = 0; nf < 4; ++nf) bv[nf] = bias[bn + wc * 64 + nf * 16 + lr];
#pragma unroll
    for (int mf = 0; mf < 2; ++mf)
#pragma unroll
        for (int r = 0; r < 4; ++r) {
            const int row = bm + wr * 32 + mf * 16 + lg * 4 + r;
            float* cp = C + (size_t)row * CDIM + bn + wc * 64;
#pragma unroll
            for (int nf = 0; nf < 4; ++nf)
                cp[nf * 16 + lr] = acc[mf][nf][r] + bv[nf];
        }
}

// -------------------- vt (1024 blocks) + sparse_kv (256 blocks) merged ----

__global__ __launch_bounds__(256) void vt_skv_kernel(const ushort_t* __restrict__ qkvd_bf,
                                                     ushort_t* __restrict__ vtg,
                                                     const float* __restrict__ qkvs,
                                                     float* __restrict__ kvpart)
{
    __shared__ __align__(16) float smem[8704];   // 34816 B
    const int t = threadIdx.x;

    if (blockIdx.x < 1024) {
        ushort_t* tile = (ushort_t*)smem;
        const int bh = blockIdx.x & 63, nt = blockIdx.x >> 6;
        const int b  = bh >> 3, h = bh & 7;
        const int row = t >> 2, c16 = (t & 3) * 16;
        const size_t src = (size_t)(b * NTOK + nt * 64 + row) * QKV_N + 2 * CDIM + h * HD + c16;
        *(short8*)(tile + row * 72 + c16)     = *(const short8*)(qkvd_bf + src);
        *(short8*)(tile + row * 72 + c16 + 8) = *(const short8*)(qkvd_bf + src + 8);
        __syncthreads();
        const int d = t >> 2, tc = (t & 3) * 16;
        short8 o0, o1;
#pragma unroll
        for (int i = 0; i < 8; ++i) {
            o0[i] = (short)tile[(tc + i) * 72 + d];
            o1[i] = (short)tile[(tc + 8 + i) * 72 + d];
        }
        const size_t dst = ((size_t)bh * 64 + d) * NTOK + nt * 64 + tc;
        *(short8*)(vtg + dst)     = o0;
        *(short8*)(vtg + dst + 8) = o1;
        return;
    }

    const int bid   = blockIdx.x - 1024;
    const int bh    = bid >> 2;
    const int chunk = bid & 3;
    const int b     = bh >> 3, h = bh & 7;
    const int j     = t >> 2, g = t & 3;
    float* ks = smem;
    float* vs = smem + 64 * 68;
    float4 acc[4];
#pragma unroll
    for (int c4 = 0; c4 < 4; ++c4) acc[c4] = make_float4(0.f, 0.f, 0.f, 0.f);

    const size_t bbase = (size_t)b * NTOK * QKV_N;
    for (int mt = chunk * 4; mt < chunk * 4 + 4; ++mt) {
        __syncthreads();
        {
            const float* ksrc = qkvs + bbase + (size_t)(mt * 64) * QKV_N + CDIM + h * HD;
            const float* vsrc = ksrc + CDIM;
#pragma unroll
            for (int i = 0; i < 4; ++i) {
                const int idx = t + i * 256;
                const int row = idx >> 4, c4 = (idx & 15) * 4;
                *(float4*)(ks + row * 68 + c4) = *(const float4*)(ksrc + (size_t)row * QKV_N + c4);
                *(float4*)(vs + row * 68 + c4) = *(const float4*)(vsrc + (size_t)row * QKV_N + c4);
            }
        }
        __syncthreads();
#pragma unroll 4
        for (int m = 0; m < 64; ++m) {
            const float kkv = ks[m * 68 + j];
            const float rk  = fmaxf(kkv, 0.f);
            const float rk2 = rk * rk;
#pragma unroll
            for (int c4 = 0; c4 < 4; ++c4) {
                const float4 vv = *(const float4*)(vs + m * 68 + g * 16 + c4 * 4);
                acc[c4].x += rk2 * vv.x; acc[c4].y += rk2 * vv.y;
                acc[c4].z += rk2 * vv.z; acc[c4].w += rk2 * vv.w;
            }
        }
    }
#pragma unroll
    for (int c4 = 0; c4 < 4; ++c4) {
        float4 w = acc[c4];
        w.x *= SCALE; w.y *= SCALE; w.z *= SCALE; w.w *= SCALE;
        *(float4*)(kvpart + ((size_t)bid << 12) + j * 64 + g * 16 + c4 * 4) = w;
    }
}

// -------------------- attention (512 blocks, QBLK=128) + sparse_out (1024) ----
// Attention: each block covers 128 q-rows (2 qh-phases per wave) against the
// K/V stream -> staging/barriers amortized over 2x compute, K/V fetch halved.
// T14 async-STAGE retained: next K/V tile loaded to regs during compute.

__global__ __launch_bounds__(256) void attn_sout_kernel(const ushort_t* __restrict__ qkvd_bf,
                                                        const ushort_t* __restrict__ vtg,
                                                        const float* __restrict__ qkvs,
                                                        const float* __restrict__ kvpart,
                                                        const float* __restrict__ fw,
                                                        ushort_t* __restrict__ athi,
                                                        ushort_t* __restrict__ atlo)
{
    __shared__ __align__(16) float smem[9216];   // 36864 B
    const int t = threadIdx.x;

    if (blockIdx.x < 512) {
        const int l  = t & 63;
        const int w  = t >> 6;
        const int lr = l & 15;
        const int lg = l >> 4;

        // XCD swizzle: 64 blocks/XCD = 8 bh x 8 q-tiles (128 rows each)
        const int blk = blockIdx.x;
        const int xcd = blk & 7;
        const int ixl = blk >> 3;                 // 0..63
        const int bh  = ((ixl >> 3) << 3) + xcd;
        const int qt  = ixl & 7;                  // 0..7
        const int b   = bh >> 3, h = bh & 7;

        ushort_t* Qs = (ushort_t*)smem;
        ushort_t* Ks = Qs + 64 * 72;
        ushort_t* Vs = Ks + 64 * 72;
        ushort_t* Pq = Vs + 64 * 72;

        const int srow = t >> 2, sc = (t & 3) * 16;
        const size_t kbase = (size_t)(b * NTOK + srow) * QKV_N + CDIM + h * HD + sc;
        const size_t vbase = ((size_t)bh * 64 + srow) * NTOK + sc;

        // stage Q for both 64-row halves (Qs reused), fragments kept in regs
        short8 bQ0[2], bQ1[2];
#pragma unroll
        for (int qh = 0; qh < 2; ++qh) {
            const size_t src = (size_t)(b * NTOK + qt * 128 + qh * 64 + srow) * QKV_N + h * HD + sc;
            *(short8*)(Qs + srow * 72 + sc)     = *(const short8*)(qkvd_bf + src);
            *(short8*)(Qs + srow * 72 + sc + 8) = *(const short8*)(qkvd_bf + src + 8);
            __syncthreads();
            bQ0[qh] = *(const short8*)(Qs + (w * 16 + lr) * 72 + lg * 8);
            bQ1[qh] = *(const short8*)(Qs + (w * 16 + lr) * 72 + 32 + lg * 8);
            __syncthreads();
        }

        // prologue: prefetch K/V tile 0 into registers
        short8 kr0 = *(const short8*)(qkvd_bf + kbase);
        short8 kr1 = *(const short8*)(qkvd_bf + kbase + 8);
        short8 vr0 = *(const short8*)(vtg + vbase);
        short8 vr1 = *(const short8*)(vtg + vbase + 8);

        f32x4 oacc[2][4];
#pragma unroll
        for (int qh = 0; qh < 2; ++qh)
#pragma unroll
            for (int i = 0; i < 4; ++i) oacc[qh][i] = (f32x4){0.f, 0.f, 0.f, 0.f};
        float lsum[2] = {0.f, 0.f};

        for (int kt2 = 0; kt2 < 16; ++kt2) {
            // write the prefetched K/V tile to LDS
            *(short8*)(Ks + srow * 72 + sc)     = kr0;
            *(short8*)(Ks + srow * 72 + sc + 8) = kr1;
            *(short8*)(Vs + srow * 72 + sc)     = vr0;
            *(short8*)(Vs + srow * 72 + sc + 8) = vr1;
            __syncthreads();

            // issue next tile's loads now; latency hides under compute below
            if (kt2 < 15) {
                const size_t ksrc = kbase + (size_t)((kt2 + 1) * 64) * QKV_N;
                const size_t vsrc = vbase + (kt2 + 1) * 64;
                kr0 = *(const short8*)(qkvd_bf + ksrc);
                kr1 = *(const short8*)(qkvd_bf + ksrc + 8);
                vr0 = *(const short8*)(vtg + vsrc);
                vr1 = *(const short8*)(vtg + vsrc + 8);
            }

#pragma unroll
            for (int qh = 0; qh < 2; ++qh) {
#pragma unroll
                for (int kb = 0; kb < 4; ++kb) {
                    const short8 aK0 = *(const short8*)(Ks + (kb * 16 + lr) * 72 + lg * 8);
                    const short8 aK1 = *(const short8*)(Ks + (kb * 16 + lr) * 72 + 32 + lg * 8);
                    f32x4 z = {0.f, 0.f, 0.f, 0.f};
                    __builtin_amdgcn_s_setprio(1);
                    z = __builtin_amdgcn_mfma_f32_16x16x32_bf16(aK0, bQ0[qh], z, 0, 0, 0);
                    z = __builtin_amdgcn_mfma_f32_16x16x32_bf16(aK1, bQ1[qh], z, 0, 0, 0);
                    __builtin_amdgcn_s_setprio(0);
                    // Q pre-scaled by SCL2E: p = 2^z directly
                    const float p0 = exp2f(z[0]);
                    const float p1 = exp2f(z[1]);
                    const float p2 = exp2f(z[2]);
                    const float p3 = exp2f(z[3]);
                    lsum[qh] += (p0 + p1) + (p2 + p3);
                    unsigned int r01, r23;
                    asm("v_cvt_pk_bf16_f32 %0, %1, %2" : "=v"(r01) : "v"(p0), "v"(p1));
                    asm("v_cvt_pk_bf16_f32 %0, %1, %2" : "=v"(r23) : "v"(p2), "v"(p3));
                    uint2 pw; pw.x = r01; pw.y = r23;
                    *(uint2*)(Pq + (w * 16 + lr) * 72 + kb * 16 + lg * 4) = pw;
                }
                // same-wave DS ordering: these reads complete before qh=1's writes
                const short8 bP0 = *(const short8*)(Pq + (w * 16 + lr) * 72 + lg * 8);
                const short8 bP1 = *(const short8*)(Pq + (w * 16 + lr) * 72 + 32 + lg * 8);
                __builtin_amdgcn_s_setprio(1);
#pragma unroll
                for (int nfd = 0; nfd < 4; ++nfd) {
                    const short8 aV0 = *(const short8*)(Vs + (nfd * 16 + lr) * 72 + lg * 8);
                    const short8 aV1 = *(const short8*)(Vs + (nfd * 16 + lr) * 72 + 32 + lg * 8);
                    oacc[qh][nfd] = __builtin_amdgcn_mfma_f32_16x16x32_bf16(aV0, bP0, oacc[qh][nfd], 0, 0, 0);
                    oacc[qh][nfd] = __builtin_amdgcn_mfma_f32_16x16x32_bf16(aV1, bP1, oacc[qh][nfd], 0, 0, 0);
                }
                __builtin_amdgcn_s_setprio(0);
            }
            __syncthreads();   // all reads of Ks/Vs done before next ds_write
        }

        float a0, a1;
        get_alpha(fw, a0, a1);
#pragma unroll
        for (int qh = 0; qh < 2; ++qh) {
            float ls = lsum[qh];
            ls += __shfl_xor(ls, 16, 64);
            ls += __shfl_xor(ls, 32, 64);
            const float sc2 = a1 / ls;
            const size_t orow = ((size_t)(b * NTOK + qt * 128 + qh * 64 + w * 16 + lr)) * 1024 + CDIM + h * HD;
#pragma unroll
            for (int nfd = 0; nfd < 4; ++nfd) {
                ushort4 hw;
#pragma unroll
                for (int r = 0; r < 4; ++r)
                    ((ushort_t*)&hw)[r] = f2bf(oacc[qh][nfd][r] * sc2);
                *(ushort4*)(athi + orow + nfd * 16 + lg * 4) = hw;
            }
        }
        return;
    }

    const int blk = blockIdx.x - 512;
    const int qt  = blk & 15;
    const int bh  = blk >> 4;
    const int b   = bh >> 3, h = bh & 7;
    const int r   = t >> 2, g = t & 3;
    float* qs  = smem;
    float* kvs = smem + 64 * 68;
    {
        const float* qsrc = qkvs + (size_t)b * NTOK * QKV_N + (size_t)(qt * 64) * QKV_N + h * HD;
        const float* p0 = kvpart + ((size_t)(bh * 4) << 12);
#pragma unroll
        for (int i = 0; i < 4; ++i) {
            const int idx = t + i * 256;
            const int row = idx >> 4, c4 = (idx & 15) * 4;
            *(float4*)(qs + row * 68 + c4) = *(const float4*)(qsrc + (size_t)row * QKV_N + c4);
            const int o = row * 64 + c4;
            float4 s0 = *(const float4*)(p0 + o);
            const float4 s1 = *(const float4*)(p0 + 4096 + o);
            const float4 s2 = *(const float4*)(p0 + 8192 + o);
            const float4 s3 = *(const float4*)(p0 + 12288 + o);
            s0.x += s1.x + s2.x + s3.x; s0.y += s1.y + s2.y + s3.y;
            s0.z += s1.z + s2.z + s3.z; s0.w += s1.w + s2.w + s3.w;
            *(float4*)(kvs + row * 68 + c4) = s0;
        }
    }
    __syncthreads();
    float4 acc[4];
#pragma unroll
    for (int c4 = 0; c4 < 4; ++c4) acc[c4] = make_float4(0.f, 0.f, 0.f, 0.f);
#pragma unroll 4
    for (int jj = 0; jj < 64; ++jj) {
        const float qv  = qs[r * 68 + jj];
        const float rq  = fmaxf(qv, 0.f);
        const float rq2 = rq * rq;
#pragma unroll
        for (int c4 = 0; c4 < 4; ++c4) {
            const float4 kvv = *(const float4*)(kvs + jj * 68 + g * 16 + c4 * 4);
            acc[c4].x += rq2 * kvv.x; acc[c4].y += rq2 * kvv.y;
            acc[c4].z += rq2 * kvv.z; acc[c4].w += rq2 * kvv.w;
        }
    }
    float a0, a1;
    get_alpha(fw, a0, a1);
    const size_t orow = ((size_t)(b * NTOK + qt * 64 + r)) * 1024 + h * HD;
#pragma unroll
    for (int c4 = 0; c4 < 4; ++c4) {
        float4 w = acc[c4];
        w.x *= a0; w.y *= a0; w.z *= a0; w.w *= a0;
        ushort4 hw, lw;
        hw.x = f2bf(w.x); lw.x = f2bf(w.x - bf2f(hw.x));
        hw.y = f2bf(w.y); lw.y = f2bf(w.y - bf2f(hw.y));
        hw.z = f2bf(w.z); lw.z = f2bf(w.z - bf2f(hw.z));
        hw.w = f2bf(w.w); lw.w = f2bf(w.w - bf2f(hw.w));
        *(ushort4*)(athi + orow + g * 16 + c4 * 4) = hw;
        *(ushort4*)(atlo + orow + g * 16 + c4 * 4) = lw;
    }
}

// -------------------- launch --------------------

extern "C" void kernel_launch(void* const* d_in, const int* in_sizes, int n_in,
                              void* d_out, int out_size, void* d_ws, size_t ws_size,
                              hipStream_t stream)
{
    (void)in_sizes; (void)n_in; (void)out_size; (void)ws_size;

    const float* x        = (const float*)d_in[0];
    const float* ln_g     = (const float*)d_in[1];
    const float* ln_b     = (const float*)d_in[2];
    const float* qkv_d_w  = (const float*)d_in[3];
    const float* qkv_d_b  = (const float*)d_in[4];
    const float* qkv_s_w  = (const float*)d_in[5];
    const float* qkv_s_b  = (const float*)d_in[6];
    const float* proj_d_w = (const float*)d_in[7];
    const float* proj_d_b = (const float*)d_in[8];
    const float* proj_s_w = (const float*)d_in[9];
    const float* proj_s_b = (const float*)d_in[10];
    const float* fw       = (const float*)d_in[11];

    float* ws = (float*)d_ws;
    // fp32
    float*    qkvs    = ws;                                  // [8192x1536] fp32
    float*    kvpart  = ws + (size_t)12582912;               // [256x64x64] fp32
    float*    biasc   = ws + (size_t)13631488;               // [512]
    // bf16 (ushort) regions, float-offset based
    ushort_t* qkvd_bf = (ushort_t*)(ws + (size_t)14680064);  // [8192x1536]
    ushort_t* vtg     = (ushort_t*)(ws + (size_t)20971520);  // [64x64x1024]
    ushort_t* athi    = (ushort_t*)(ws + (size_t)23068672);  // [8192x1024]
    ushort_t* atlo    = (ushort_t*)(ws + (size_t)27262976);  // [8192x1024]
    ushort_t* xhi     = (ushort_t*)(ws + (size_t)31457280);  // [8192x512]
    ushort_t* xlo     = (ushort_t*)(ws + (size_t)33554432);  // [8192x512]
    ushort_t* WdT_hi  = (ushort_t*)(ws + (size_t)35651584);  // [1536x512]
    ushort_t* WsT_hi  = (ushort_t*)(ws + (size_t)36044800);  // [1536x512]
    ushort_t* WsT_lo  = (ushort_t*)(ws + (size_t)36438016);  // [1536x512]
    ushort_t* WpT_hi  = (ushort_t*)(ws + (size_t)36831232);  // [512x1024]
    ushort_t* WpT_lo  = (ushort_t*)(ws + (size_t)37093376);  // [512x1024]

    prep_kernel<<<2561, 256, 0, stream>>>(x, ln_g, ln_b, xhi, xlo,
                                          qkv_d_w, WdT_hi,
                                          qkv_s_w, WsT_hi, WsT_lo,
                                          proj_s_w, proj_d_w, WpT_hi, WpT_lo,
                                          proj_s_b, proj_d_b, fw, biasc);

    gemm_bf16_mfma<0, 1><<<dim3(64, 12), 256, 0, stream>>>(xhi, nullptr, WdT_hi, nullptr,
                                                           qkv_d_b, nullptr, qkvd_bf,
                                                           QKV_N, CDIM);
    gemm_bf16_mfma<1, 0><<<dim3(64, 12), 256, 0, stream>>>(xhi, xlo, WsT_hi, WsT_lo,
                                                           qkv_s_b, qkvs, nullptr,
                                                           QKV_N, CDIM);

    vt_skv_kernel<<<1280, 256, 0, stream>>>(qkvd_bf, vtg, qkvs, kvpart);
    attn_sout_kernel<<<1536, 256, 0, stream>>>(qkvd_bf, vtg, qkvs, kvpart, fw, athi, atlo);

    gemm_proj<<<dim3(128, 4), 256, 0, stream>>>(athi, atlo, WpT_hi, WpT_lo,
                                                biasc, (float*)d_out);
}

// Round 25
// 176.607 us; speedup vs baseline: 1.0107x; 1.0107x over previous
//
#include <hip/hip_runtime.h>
#include <math.h>

// x: [8, 32, 32, 512] -> rows M = 8192, C = 512, heads = 8, hd = 64
#define M_ROWS   8192
#define CDIM     512
#define QKV_N    1536
#define NTOK     1024
#define HEADS    8
#define HD       64
#define EPS      1e-3f
#define SCALE    0.125f   // 64^-0.5
#define SCL2E    0.18033688011112042f   // SCALE * log2(e)

typedef __attribute__((ext_vector_type(8))) short short8;
typedef __attribute__((ext_vector_type(4))) float f32x4;
typedef unsigned short ushort_t;

// -------------------- helpers --------------------

__device__ __forceinline__ ushort_t f2bf(float f) {
    union { float f; unsigned int u; } v; v.f = f;
    unsigned int r = v.u + 0x7fffu + ((v.u >> 16) & 1u);   // RNE
    return (ushort_t)(r >> 16);
}
__device__ __forceinline__ float bf2f(ushort_t u) {
    union { unsigned int u; float f; } v; v.u = ((unsigned int)u) << 16;
    return v.f;
}

// async global->LDS 16B copy: per-lane global src, wave-uniform LDS base
// (HW adds lane*16). Drained by the vmcnt(0) the compiler emits at barriers.
__device__ __forceinline__ void stage16(const void* g, void* l) {
    __builtin_amdgcn_global_load_lds(
        (__attribute__((address_space(1))) void*)(g),
        (__attribute__((address_space(3))) void*)(l), 16, 0, 0);
}

__device__ __forceinline__ void get_alpha(const float* __restrict__ fw,
                                          float& a0, float& a1)
{
    const float m  = fmaxf(fw[0], fw[1]);
    const float e0 = __expf(fw[0] - m);
    const float e1 = __expf(fw[1] - m);
    const float inv = 1.0f / (e0 + e1);
    a0 = e0 * inv;   // sparse
    a1 = e1 * inv;   // dense
}

// -------------------- prep: ln (2048x4 rows) + tconv x4 (512) + bias (1) ----

__device__ __forceinline__ void tconv_body(const float* __restrict__ W,
                                           ushort_t* __restrict__ hiT,
                                           ushort_t* __restrict__ loT,
                                           int N, int ors, int coff,
                                           int bk, int bn, int t,
                                           float (*tile)[65])
{
#pragma unroll
    for (int i = 0; i < 4; ++i) {
        const int idx = t + i * 256;
        const int kl = idx >> 4, nl = (idx & 15) * 4;
        const float4 v = *(const float4*)(W + (size_t)(bk + kl) * N + bn + nl);
        tile[kl][nl] = v.x; tile[kl][nl + 1] = v.y;
        tile[kl][nl + 2] = v.z; tile[kl][nl + 3] = v.w;
    }
    __syncthreads();
#pragma unroll
    for (int i = 0; i < 2; ++i) {
        const int idx = t + i * 256;
        const int nl = idx >> 3, kc = (idx & 7) * 8;
        short8 hv, lv;
#pragma unroll
        for (int j = 0; j < 8; ++j) {
            const float f = tile[kc + j][nl];
            const ushort_t h = f2bf(f);
            hv[j] = (short)h;
            lv[j] = (short)f2bf(f - bf2f(h));
        }
        const size_t ob = (size_t)(bn + nl) * ors + coff + bk + kc;
        *(short8*)(hiT + ob) = hv;
        if (loT) *(short8*)(loT + ob) = lv;
    }
}

__global__ __launch_bounds__(256) void prep_kernel(const float* __restrict__ x,
                                                   const float* __restrict__ gamma,
                                                   const float* __restrict__ beta,
                                                   ushort_t* __restrict__ xhi,
                                                   ushort_t* __restrict__ xlo,
                                                   const float* __restrict__ qkv_d_w,
                                                   ushort_t* __restrict__ WdT_hi,
                                                   const float* __restrict__ qkv_s_w,
                                                   ushort_t* __restrict__ WsT_hi,
                                                   ushort_t* __restrict__ WsT_lo,
                                                   const float* __restrict__ proj_s_w,
                                                   const float* __restrict__ proj_d_w,
                                                   ushort_t* __restrict__ WpT_hi,
                                                   ushort_t* __restrict__ WpT_lo,
                                                   const float* __restrict__ bs,
                                                   const float* __restrict__ bd,
                                                   const float* __restrict__ fw,
                                                   float* __restrict__ biasc)
{
    __shared__ float tile[64][65];
    const int t = threadIdx.x;
    const int blk = blockIdx.x;

    if (blk < 2048) {
        // ---- LayerNorm: one wave per row, wave-local reduce (no barriers) ----
        const int wv   = t >> 6, lane = t & 63;
        const int row  = blk * 4 + wv;
        const float* xr = x + (size_t)row * CDIM + lane * 8;
        const float4 v0 = *(const float4*)(xr);
        const float4 v1 = *(const float4*)(xr + 4);
        float s  = (v0.x + v0.y) + (v0.z + v0.w) + (v1.x + v1.y) + (v1.z + v1.w);
        float ss = (v0.x * v0.x + v0.y * v0.y) + (v0.z * v0.z + v0.w * v0.w)
                 + (v1.x * v1.x + v1.y * v1.y) + (v1.z * v1.z + v1.w * v1.w);
#pragma unroll
        for (int off = 32; off > 0; off >>= 1) {
            s  += __shfl_xor(s,  off, 64);
            ss += __shfl_xor(ss, off, 64);
        }
        const float mu  = s * (1.0f / CDIM);
        const float var = ss * (1.0f / CDIM) - mu * mu;
        const float rs  = rsqrtf(var + EPS);
        const float4 g0 = *(const float4*)(gamma + lane * 8);
        const float4 g1 = *(const float4*)(gamma + lane * 8 + 4);
        const float4 b0 = *(const float4*)(beta + lane * 8);
        const float4 b1 = *(const float4*)(beta + lane * 8 + 4);
        float o[8];
        o[0] = (v0.x - mu) * rs * g0.x + b0.x;
        o[1] = (v0.y - mu) * rs * g0.y + b0.y;
        o[2] = (v0.z - mu) * rs * g0.z + b0.z;
        o[3] = (v0.w - mu) * rs * g0.w + b0.w;
        o[4] = (v1.x - mu) * rs * g1.x + b1.x;
        o[5] = (v1.y - mu) * rs * g1.y + b1.y;
        o[6] = (v1.z - mu) * rs * g1.z + b1.z;
        o[7] = (v1.w - mu) * rs * g1.w + b1.w;
        short8 hv, lv;
#pragma unroll
        for (int j = 0; j < 8; ++j) {
            const ushort_t h = f2bf(o[j]);
            hv[j] = (short)h;
            lv[j] = (short)f2bf(o[j] - bf2f(h));
        }
        *(short8*)(xhi + (size_t)row * CDIM + lane * 8) = hv;
        *(short8*)(xlo + (size_t)row * CDIM + lane * 8) = lv;
        return;
    }
    int idx = blk - 2048;
    if (idx < 192) {
        tconv_body(qkv_d_w, WdT_hi, nullptr, QKV_N, CDIM, 0,
                   (idx & 7) * 64, (idx >> 3) * 64, t, tile);
        return;
    }
    idx -= 192;
    if (idx < 192) {
        tconv_body(qkv_s_w, WsT_hi, WsT_lo, QKV_N, CDIM, 0,
                   (idx & 7) * 64, (idx >> 3) * 64, t, tile);
        return;
    }
    idx -= 192;
    if (idx < 64) {
        tconv_body(proj_s_w, WpT_hi, WpT_lo, CDIM, 1024, 0,
                   (idx & 7) * 64, (idx >> 3) * 64, t, tile);
        return;
    }
    idx -= 64;
    if (idx < 64) {
        tconv_body(proj_d_w, WpT_hi, nullptr, CDIM, 1024, 512,
                   (idx & 7) * 64, (idx >> 3) * 64, t, tile);
        return;
    }
    float a0, a1;
    get_alpha(fw, a0, a1);
    biasc[t]       = a0 * bs[t]       + a1 * bd[t];
    biasc[t + 256] = a0 * bs[t + 256] + a1 * bd[t + 256];
}

// -------------------- bf16 MFMA GEMM: C = A @ B^T + bias --------------------
// MODE 0: plain 1-MFMA. MODE 1: full split (3-MFMA). OUTBF=1: bf16 output to Cb,
// with Q columns (col < 512) pre-scaled by SCL2E so attention skips the
// per-logit scale mul (exact: softmax scale folded into Q).

template<int MODE, int OUTBF>
__global__ __launch_bounds__(256) void gemm_bf16_mfma(const ushort_t* __restrict__ Ahi,
                                                      const ushort_t* __restrict__ Alo,
                                                      const ushort_t* __restrict__ Bhi,
                                                      const ushort_t* __restrict__ Blo,
                                                      const float* __restrict__ bias,
                                                      float* __restrict__ C,
                                                      ushort_t* __restrict__ Cb,
                                                      int N, int K)
{
    const int t  = threadIdx.x;
    const int l  = t & 63, w = t >> 6;
    const int wr = w >> 1, wc = w & 1;
    const int lr = l & 15, lg = l >> 4;
    const int bm = blockIdx.x * 128, bn = blockIdx.y * 128;

    __shared__ ushort_t As[MODE ? 2 : 1][128 * 64];
    __shared__ ushort_t Bs[MODE ? 2 : 1][128 * 64];

    f32x4 acc[4][4];
#pragma unroll
    for (int i = 0; i < 4; ++i)
#pragma unroll
        for (int j = 0; j < 4; ++j) acc[i][j] = (f32x4){0.f, 0.f, 0.f, 0.f};

    const int srow8 = t >> 3;                              // 0..31
    const int sch   = ((t & 7) ^ ((t >> 3) & 7)) * 8;      // pre-swizzled src chunk
    const int lbase = (t >> 6) * 512;                      // wave-uniform LDS base

    for (int kt = 0; kt < K; kt += 64) {
        __syncthreads();
#pragma unroll
        for (int i = 0; i < 4; ++i) {
            const int row = srow8 + i * 32;
            const size_t ga = (size_t)(bm + row) * K + kt + sch;
            const size_t gb = (size_t)(bn + row) * K + kt + sch;
            stage16(Ahi + ga, &As[0][i * 2048 + lbase]);
            stage16(Bhi + gb, &Bs[0][i * 2048 + lbase]);
            if (MODE) {
                stage16(Alo + ga, &As[MODE ? 1 : 0][i * 2048 + lbase]);
                stage16(Blo + gb, &Bs[MODE ? 1 : 0][i * 2048 + lbase]);
            }
        }
        __syncthreads();
#pragma unroll
        for (int ks = 0; ks < 2; ++ks) {
            short8 ah[4], bh[4], al[4], bl[4];
#pragma unroll
            for (int mf = 0; mf < 4; ++mf) {
                const int row = wr * 64 + mf * 16 + lr;
                const int cs  = (((ks * 4 + lg) ^ (row & 7)) * 8);
                ah[mf] = *(const short8*)(&As[0][row * 64 + cs]);
                if (MODE) al[mf] = *(const short8*)(&As[MODE ? 1 : 0][row * 64 + cs]);
            }
#pragma unroll
            for (int nf = 0; nf < 4; ++nf) {
                const int row = wc * 64 + nf * 16 + lr;
                const int cs  = (((ks * 4 + lg) ^ (row & 7)) * 8);
                bh[nf] = *(const short8*)(&Bs[0][row * 64 + cs]);
                if (MODE) bl[nf] = *(const short8*)(&Bs[MODE ? 1 : 0][row * 64 + cs]);
            }
#pragma unroll
            for (int mf = 0; mf < 4; ++mf)
#pragma unroll
                for (int nf = 0; nf < 4; ++nf) {
                    acc[mf][nf] = __builtin_amdgcn_mfma_f32_16x16x32_bf16(ah[mf], bh[nf], acc[mf][nf], 0, 0, 0);
                    if (MODE) {
                        acc[mf][nf] = __builtin_amdgcn_mfma_f32_16x16x32_bf16(al[mf], bh[nf], acc[mf][nf], 0, 0, 0);
                        acc[mf][nf] = __builtin_amdgcn_mfma_f32_16x16x32_bf16(ah[mf], bl[nf], acc[mf][nf], 0, 0, 0);
                    }
                }
        }
    }
    float bv[4];
#pragma unroll
    for (int nf = 0; nf < 4; ++nf) bv[nf] = bias[bn + wc * 64 + nf * 16 + lr];
    const float oscl = (OUTBF && bn < 512) ? SCL2E : 1.0f;   // Q pre-scale
#pragma unroll
    for (int mf = 0; mf < 4; ++mf)
#pragma unroll
        for (int r = 0; r < 4; ++r) {
            const int row = bm + wr * 64 + mf * 16 + lg * 4 + r;
            if (OUTBF) {
                ushort_t* cp = Cb + (size_t)row * N + bn + wc * 64;
#pragma unroll
                for (int nf = 0; nf < 4; ++nf)
                    cp[nf * 16 + lr] = f2bf((acc[mf][nf][r] + bv[nf]) * oscl);
            } else {
                float* cp = C + (size_t)row * N + bn + wc * 64;
#pragma unroll
                for (int nf = 0; nf < 4; ++nf)
                    cp[nf * 16 + lr] = acc[mf][nf][r] + bv[nf];
            }
        }
}

// -------------------- proj GEMM: BM=64 x BN=128, static K-split precision ----

__global__ __launch_bounds__(256) void gemm_proj(const ushort_t* __restrict__ Ahi,
                                                 const ushort_t* __restrict__ Alo,
                                                 const ushort_t* __restrict__ Bhi,
                                                 const ushort_t* __restrict__ Blo,
                                                 const float* __restrict__ bias,
                                                 float* __restrict__ C)
{
    const int t  = threadIdx.x;
    const int l  = t & 63, w = t >> 6;
    const int wr = w >> 1, wc = w & 1;
    const int lr = l & 15, lg = l >> 4;
    const int bm = blockIdx.x * 64, bn = blockIdx.y * 128;

    __shared__ ushort_t As[2][64 * 64];
    __shared__ ushort_t Bs[2][128 * 64];

    f32x4 acc[2][4];
#pragma unroll
    for (int i = 0; i < 2; ++i)
#pragma unroll
        for (int j = 0; j < 4; ++j) acc[i][j] = (f32x4){0.f, 0.f, 0.f, 0.f};

    const int srow8 = t >> 3;                              // 0..31
    const int sch   = ((t & 7) ^ ((t >> 3) & 7)) * 8;
    const int lbase = (t >> 6) * 512;

    // ---- sparse K-half: split precision (3-MFMA) ----
    for (int kt = 0; kt < 512; kt += 64) {
        __syncthreads();
#pragma unroll
        for (int i = 0; i < 2; ++i) {
            const size_t ga = (size_t)(bm + srow8 + i * 32) * 1024 + kt + sch;
            stage16(Ahi + ga, &As[0][i * 2048 + lbase]);
            stage16(Alo + ga, &As[1][i * 2048 + lbase]);
        }
#pragma unroll
        for (int i = 0; i < 4; ++i) {
            const size_t gb = (size_t)(bn + srow8 + i * 32) * 1024 + kt + sch;
            stage16(Bhi + gb, &Bs[0][i * 2048 + lbase]);
            stage16(Blo + gb, &Bs[1][i * 2048 + lbase]);
        }
        __syncthreads();
#pragma unroll
        for (int ks = 0; ks < 2; ++ks) {
            short8 ah[2], al[2], bh[4], bl[4];
#pragma unroll
            for (int mf = 0; mf < 2; ++mf) {
                const int row = wr * 32 + mf * 16 + lr;
                const int cs  = (((ks * 4 + lg) ^ (row & 7)) * 8);
                ah[mf] = *(const short8*)(&As[0][row * 64 + cs]);
                al[mf] = *(const short8*)(&As[1][row * 64 + cs]);
            }
#pragma unroll
            for (int nf = 0; nf < 4; ++nf) {
                const int row = wc * 64 + nf * 16 + lr;
                const int cs  = (((ks * 4 + lg) ^ (row & 7)) * 8);
                bh[nf] = *(const short8*)(&Bs[0][row * 64 + cs]);
                bl[nf] = *(const short8*)(&Bs[1][row * 64 + cs]);
            }
#pragma unroll
            for (int mf = 0; mf < 2; ++mf)
#pragma unroll
                for (int nf = 0; nf < 4; ++nf) {
                    acc[mf][nf] = __builtin_amdgcn_mfma_f32_16x16x32_bf16(ah[mf], bh[nf], acc[mf][nf], 0, 0, 0);
                    acc[mf][nf] = __builtin_amdgcn_mfma_f32_16x16x32_bf16(al[mf], bh[nf], acc[mf][nf], 0, 0, 0);
                    acc[mf][nf] = __builtin_amdgcn_mfma_f32_16x16x32_bf16(ah[mf], bl[nf], acc[mf][nf], 0, 0, 0);
                }
        }
    }

    // ---- dense K-half: plain bf16 (1-MFMA) ----
    for (int kt = 512; kt < 1024; kt += 64) {
        __syncthreads();
#pragma unroll
        for (int i = 0; i < 2; ++i) {
            const size_t ga = (size_t)(bm + srow8 + i * 32) * 1024 + kt + sch;
            stage16(Ahi + ga, &As[0][i * 2048 + lbase]);
        }
#pragma unroll
        for (int i = 0; i < 4; ++i) {
            const size_t gb = (size_t)(bn + srow8 + i * 32) * 1024 + kt + sch;
            stage16(Bhi + gb, &Bs[0][i * 2048 + lbase]);
        }
        __syncthreads();
#pragma unroll
        for (int ks = 0; ks < 2; ++ks) {
            short8 ah[2], bh[4];
#pragma unroll
            for (int mf = 0; mf < 2; ++mf) {
                const int row = wr * 32 + mf * 16 + lr;
                const int cs  = (((ks * 4 + lg) ^ (row & 7)) * 8);
                ah[mf] = *(const short8*)(&As[0][row * 64 + cs]);
            }
#pragma unroll
            for (int nf = 0; nf < 4; ++nf) {
                const int row = wc * 64 + nf * 16 + lr;
                const int cs  = (((ks * 4 + lg) ^ (row & 7)) * 8);
                bh[nf] = *(const short8*)(&Bs[0][row * 64 + cs]);
            }
#pragma unroll
            for (int mf = 0; mf < 2; ++mf)
#pragma unroll
                for (int nf = 0; nf < 4; ++nf)
                    acc[mf][nf] = __builtin_amdgcn_mfma_f32_16x16x32_bf16(ah[mf], bh[nf], acc[mf][nf], 0, 0, 0);
        }
    }

    float bv[4];
#pragma unroll
    for (int nf = 0; nf < 4; ++nf) bv[nf] = bias[bn + wc * 64 + nf * 16 + lr];
#pragma unroll
    for (int mf = 0; mf < 2; ++mf)
#pragma unroll
        for (int r = 0; r < 4; ++r) {
            const int row = bm + wr * 32 + mf * 16 + lg * 4 + r;
            float* cp = C + (size_t)row * CDIM + bn + wc * 64;
#pragma unroll
            for (int nf = 0; nf < 4; ++nf)
                cp[nf * 16 + lr] = acc[mf][nf][r] + bv[nf];
        }
}

// -------------------- vt (1024 blocks) + sparse_kv (256 blocks) merged ----

__global__ __launch_bounds__(256) void vt_skv_kernel(const ushort_t* __restrict__ qkvd_bf,
                                                     ushort_t* __restrict__ vtg,
                                                     const float* __restrict__ qkvs,
                                                     float* __restrict__ kvpart)
{
    __shared__ __align__(16) float smem[8704];   // 34816 B
    const int t = threadIdx.x;

    if (blockIdx.x < 1024) {
        ushort_t* tile = (ushort_t*)smem;
        const int bh = blockIdx.x & 63, nt = blockIdx.x >> 6;
        const int b  = bh >> 3, h = bh & 7;
        const int row = t >> 2, c16 = (t & 3) * 16;
        const size_t src = (size_t)(b * NTOK + nt * 64 + row) * QKV_N + 2 * CDIM + h * HD + c16;
        *(short8*)(tile + row * 72 + c16)     = *(const short8*)(qkvd_bf + src);
        *(short8*)(tile + row * 72 + c16 + 8) = *(const short8*)(qkvd_bf + src + 8);
        __syncthreads();
        const int d = t >> 2, tc = (t & 3) * 16;
        short8 o0, o1;
#pragma unroll
        for (int i = 0; i < 8; ++i) {
            o0[i] = (short)tile[(tc + i) * 72 + d];
            o1[i] = (short)tile[(tc + 8 + i) * 72 + d];
        }
        const size_t dst = ((size_t)bh * 64 + d) * NTOK + nt * 64 + tc;
        *(short8*)(vtg + dst)     = o0;
        *(short8*)(vtg + dst + 8) = o1;
        return;
    }

    const int bid   = blockIdx.x - 1024;
    const int bh    = bid >> 2;
    const int chunk = bid & 3;
    const int b     = bh >> 3, h = bh & 7;
    const int j     = t >> 2, g = t & 3;
    float* ks = smem;
    float* vs = smem + 64 * 68;
    float4 acc[4];
#pragma unroll
    for (int c4 = 0; c4 < 4; ++c4) acc[c4] = make_float4(0.f, 0.f, 0.f, 0.f);

    const size_t bbase = (size_t)b * NTOK * QKV_N;
    for (int mt = chunk * 4; mt < chunk * 4 + 4; ++mt) {
        __syncthreads();
        {
            const float* ksrc = qkvs + bbase + (size_t)(mt * 64) * QKV_N + CDIM + h * HD;
            const float* vsrc = ksrc + CDIM;
#pragma unroll
            for (int i = 0; i < 4; ++i) {
                const int idx = t + i * 256;
                const int row = idx >> 4, c4 = (idx & 15) * 4;
                *(float4*)(ks + row * 68 + c4) = *(const float4*)(ksrc + (size_t)row * QKV_N + c4);
                *(float4*)(vs + row * 68 + c4) = *(const float4*)(vsrc + (size_t)row * QKV_N + c4);
            }
        }
        __syncthreads();
#pragma unroll 4
        for (int m = 0; m < 64; ++m) {
            const float kkv = ks[m * 68 + j];
            const float rk  = fmaxf(kkv, 0.f);
            const float rk2 = rk * rk;
#pragma unroll
            for (int c4 = 0; c4 < 4; ++c4) {
                const float4 vv = *(const float4*)(vs + m * 68 + g * 16 + c4 * 4);
                acc[c4].x += rk2 * vv.x; acc[c4].y += rk2 * vv.y;
                acc[c4].z += rk2 * vv.z; acc[c4].w += rk2 * vv.w;
            }
        }
    }
#pragma unroll
    for (int c4 = 0; c4 < 4; ++c4) {
        float4 w = acc[c4];
        w.x *= SCALE; w.y *= SCALE; w.z *= SCALE; w.w *= SCALE;
        *(float4*)(kvpart + ((size_t)bid << 12) + j * 64 + g * 16 + c4 * 4) = w;
    }
}

// -------------------- attention (1024 blocks) + sparse_out (1024 blocks) merged ----
// Attention half uses T14 async-STAGE: K/V loaded to regs one tile ahead
// (issued right after the post-write barrier), ds_write'd at loop top.
// HBM latency hides under the QK/softmax/PV compute phase.

__global__ __launch_bounds__(256) void attn_sout_kernel(const ushort_t* __restrict__ qkvd_bf,
                                                        const ushort_t* __restrict__ vtg,
                                                        const float* __restrict__ qkvs,
                                                        const float* __restrict__ kvpart,
                                                        const float* __restrict__ fw,
                                                        ushort_t* __restrict__ athi,
                                                        ushort_t* __restrict__ atlo)
{
    __shared__ __align__(16) float smem[9216];   // 36864 B
    const int t = threadIdx.x;

    if (blockIdx.x < 1024) {
        const int l  = t & 63;
        const int w  = t >> 6;
        const int lr = l & 15;
        const int lg = l >> 4;

        const int blk = blockIdx.x;
        const int xcd = blk & 7;
        const int ixl = blk >> 3;
        const int bh  = ((ixl >> 4) << 3) + xcd;
        const int qt  = ixl & 15;
        const int b   = bh >> 3, h = bh & 7;

        ushort_t* Qs = (ushort_t*)smem;
        ushort_t* Ks = Qs + 64 * 72;
        ushort_t* Vs = Ks + 64 * 72;
        ushort_t* Pq = Vs + 64 * 72;

        const int srow = t >> 2, sc = (t & 3) * 16;
        const size_t kbase = (size_t)(b * NTOK + srow) * QKV_N + CDIM + h * HD + sc;
        const size_t vbase = ((size_t)bh * 64 + srow) * NTOK + sc;

        {
            const size_t src = (size_t)(b * NTOK + qt * 64 + srow) * QKV_N + h * HD + sc;
            *(short8*)(Qs + srow * 72 + sc)     = *(const short8*)(qkvd_bf + src);
            *(short8*)(Qs + srow * 72 + sc + 8) = *(const short8*)(qkvd_bf + src + 8);
        }

        // prologue: prefetch K/V tile 0 into registers
        short8 kr0 = *(const short8*)(qkvd_bf + kbase);
        short8 kr1 = *(const short8*)(qkvd_bf + kbase + 8);
        short8 vr0 = *(const short8*)(vtg + vbase);
        short8 vr1 = *(const short8*)(vtg + vbase + 8);

        __syncthreads();

        const short8 bQ0 = *(const short8*)(Qs + (w * 16 + lr) * 72 + lg * 8);
        const short8 bQ1 = *(const short8*)(Qs + (w * 16 + lr) * 72 + 32 + lg * 8);

        f32x4 oacc[4];
#pragma unroll
        for (int i = 0; i < 4; ++i) oacc[i] = (f32x4){0.f, 0.f, 0.f, 0.f};
        float lsum = 0.f;

        for (int kt2 = 0; kt2 < 16; ++kt2) {
            // write the prefetched K/V tile to LDS
            *(short8*)(Ks + srow * 72 + sc)     = kr0;
            *(short8*)(Ks + srow * 72 + sc + 8) = kr1;
            *(short8*)(Vs + srow * 72 + sc)     = vr0;
            *(short8*)(Vs + srow * 72 + sc + 8) = vr1;
            __syncthreads();

            // issue next tile's loads now; latency hides under compute below
            if (kt2 < 15) {
                const size_t ksrc = kbase + (size_t)((kt2 + 1) * 64) * QKV_N;
                const size_t vsrc = vbase + (kt2 + 1) * 64;
                kr0 = *(const short8*)(qkvd_bf + ksrc);
                kr1 = *(const short8*)(qkvd_bf + ksrc + 8);
                vr0 = *(const short8*)(vtg + vsrc);
                vr1 = *(const short8*)(vtg + vsrc + 8);
            }

#pragma unroll
            for (int kb = 0; kb < 4; ++kb) {
                const short8 aK0 = *(const short8*)(Ks + (kb * 16 + lr) * 72 + lg * 8);
                const short8 aK1 = *(const short8*)(Ks + (kb * 16 + lr) * 72 + 32 + lg * 8);
                f32x4 z = {0.f, 0.f, 0.f, 0.f};
                __builtin_amdgcn_s_setprio(1);
                z = __builtin_amdgcn_mfma_f32_16x16x32_bf16(aK0, bQ0, z, 0, 0, 0);
                z = __builtin_amdgcn_mfma_f32_16x16x32_bf16(aK1, bQ1, z, 0, 0, 0);
                __builtin_amdgcn_s_setprio(0);
                // Q pre-scaled by SCL2E in the qkv_d GEMM: p = 2^z directly
                const float p0 = exp2f(z[0]);
                const float p1 = exp2f(z[1]);
                const float p2 = exp2f(z[2]);
                const float p3 = exp2f(z[3]);
                lsum += (p0 + p1) + (p2 + p3);
                unsigned int r01, r23;
                asm("v_cvt_pk_bf16_f32 %0, %1, %2" : "=v"(r01) : "v"(p0), "v"(p1));
                asm("v_cvt_pk_bf16_f32 %0, %1, %2" : "=v"(r23) : "v"(p2), "v"(p3));
                uint2 pw; pw.x = r01; pw.y = r23;
                *(uint2*)(Pq + (w * 16 + lr) * 72 + kb * 16 + lg * 4) = pw;
            }

            const short8 bP0 = *(const short8*)(Pq + (w * 16 + lr) * 72 + lg * 8);
            const short8 bP1 = *(const short8*)(Pq + (w * 16 + lr) * 72 + 32 + lg * 8);
            __builtin_amdgcn_s_setprio(1);
#pragma unroll
            for (int nfd = 0; nfd < 4; ++nfd) {
                const short8 aV0 = *(const short8*)(Vs + (nfd * 16 + lr) * 72 + lg * 8);
                const short8 aV1 = *(const short8*)(Vs + (nfd * 16 + lr) * 72 + 32 + lg * 8);
                oacc[nfd] = __builtin_amdgcn_mfma_f32_16x16x32_bf16(aV0, bP0, oacc[nfd], 0, 0, 0);
                oacc[nfd] = __builtin_amdgcn_mfma_f32_16x16x32_bf16(aV1, bP1, oacc[nfd], 0, 0, 0);
            }
            __builtin_amdgcn_s_setprio(0);
            __syncthreads();   // all reads of Ks/Vs done before next ds_write
        }

        lsum += __shfl_xor(lsum, 16, 64);
        lsum += __shfl_xor(lsum, 32, 64);
        float a0, a1;
        get_alpha(fw, a0, a1);
        const float sc2 = a1 / lsum;
        const size_t orow = ((size_t)(b * NTOK + qt * 64 + w * 16 + lr)) * 1024 + CDIM + h * HD;
#pragma unroll
        for (int nfd = 0; nfd < 4; ++nfd) {
            ushort4 hw;
#pragma unroll
            for (int r = 0; r < 4; ++r)
                ((ushort_t*)&hw)[r] = f2bf(oacc[nfd][r] * sc2);
            *(ushort4*)(athi + orow + nfd * 16 + lg * 4) = hw;
        }
        return;
    }

    const int blk = blockIdx.x - 1024;
    const int qt  = blk & 15;
    const int bh  = blk >> 4;
    const int b   = bh >> 3, h = bh & 7;
    const int r   = t >> 2, g = t & 3;
    float* qs  = smem;
    float* kvs = smem + 64 * 68;
    {
        const float* qsrc = qkvs + (size_t)b * NTOK * QKV_N + (size_t)(qt * 64) * QKV_N + h * HD;
        const float* p0 = kvpart + ((size_t)(bh * 4) << 12);
#pragma unroll
        for (int i = 0; i < 4; ++i) {
            const int idx = t + i * 256;
            const int row = idx >> 4, c4 = (idx & 15) * 4;
            *(float4*)(qs + row * 68 + c4) = *(const float4*)(qsrc + (size_t)row * QKV_N + c4);
            const int o = row * 64 + c4;
            float4 s0 = *(const float4*)(p0 + o);
            const float4 s1 = *(const float4*)(p0 + 4096 + o);
            const float4 s2 = *(const float4*)(p0 + 8192 + o);
            const float4 s3 = *(const float4*)(p0 + 12288 + o);
            s0.x += s1.x + s2.x + s3.x; s0.y += s1.y + s2.y + s3.y;
            s0.z += s1.z + s2.z + s3.z; s0.w += s1.w + s2.w + s3.w;
            *(float4*)(kvs + row * 68 + c4) = s0;
        }
    }
    __syncthreads();
    float4 acc[4];
#pragma unroll
    for (int c4 = 0; c4 < 4; ++c4) acc[c4] = make_float4(0.f, 0.f, 0.f, 0.f);
#pragma unroll 4
    for (int jj = 0; jj < 64; ++jj) {
        const float qv  = qs[r * 68 + jj];
        const float rq  = fmaxf(qv, 0.f);
        const float rq2 = rq * rq;
#pragma unroll
        for (int c4 = 0; c4 < 4; ++c4) {
            const float4 kvv = *(const float4*)(kvs + jj * 68 + g * 16 + c4 * 4);
            acc[c4].x += rq2 * kvv.x; acc[c4].y += rq2 * kvv.y;
            acc[c4].z += rq2 * kvv.z; acc[c4].w += rq2 * kvv.w;
        }
    }
    float a0, a1;
    get_alpha(fw, a0, a1);
    const size_t orow = ((size_t)(b * NTOK + qt * 64 + r)) * 1024 + h * HD;
#pragma unroll
    for (int c4 = 0; c4 < 4; ++c4) {
        float4 w = acc[c4];
        w.x *= a0; w.y *= a0; w.z *= a0; w.w *= a0;
        ushort4 hw, lw;
        hw.x = f2bf(w.x); lw.x = f2bf(w.x - bf2f(hw.x));
        hw.y = f2bf(w.y); lw.y = f2bf(w.y - bf2f(hw.y));
        hw.z = f2bf(w.z); lw.z = f2bf(w.z - bf2f(hw.z));
        hw.w = f2bf(w.w); lw.w = f2bf(w.w - bf2f(hw.w));
        *(ushort4*)(athi + orow + g * 16 + c4 * 4) = hw;
        *(ushort4*)(atlo + orow + g * 16 + c4 * 4) = lw;
    }
}

// -------------------- launch --------------------

extern "C" void kernel_launch(void* const* d_in, const int* in_sizes, int n_in,
                              void* d_out, int out_size, void* d_ws, size_t ws_size,
                              hipStream_t stream)
{
    (void)in_sizes; (void)n_in; (void)out_size; (void)ws_size;

    const float* x        = (const float*)d_in[0];
    const float* ln_g     = (const float*)d_in[1];
    const float* ln_b     = (const float*)d_in[2];
    const float* qkv_d_w  = (const float*)d_in[3];
    const float* qkv_d_b  = (const float*)d_in[4];
    const float* qkv_s_w  = (const float*)d_in[5];
    const float* qkv_s_b  = (const float*)d_in[6];
    const float* proj_d_w = (const float*)d_in[7];
    const float* proj_d_b = (const float*)d_in[8];
    const float* proj_s_w = (const float*)d_in[9];
    const float* proj_s_b = (const float*)d_in[10];
    const float* fw       = (const float*)d_in[11];

    float* ws = (float*)d_ws;
    // fp32
    float*    qkvs    = ws;                                  // [8192x1536] fp32
    float*    kvpart  = ws + (size_t)12582912;               // [256x64x64] fp32
    float*    biasc   = ws + (size_t)13631488;               // [512]
    // bf16 (ushort) regions, float-offset based
    ushort_t* qkvd_bf = (ushort_t*)(ws + (size_t)14680064);  // [8192x1536]
    ushort_t* vtg     = (ushort_t*)(ws + (size_t)20971520);  // [64x64x1024]
    ushort_t* athi    = (ushort_t*)(ws + (size_t)23068672);  // [8192x1024]
    ushort_t* atlo    = (ushort_t*)(ws + (size_t)27262976);  // [8192x1024]
    ushort_t* xhi     = (ushort_t*)(ws + (size_t)31457280);  // [8192x512]
    ushort_t* xlo     = (ushort_t*)(ws + (size_t)33554432);  // [8192x512]
    ushort_t* WdT_hi  = (ushort_t*)(ws + (size_t)35651584);  // [1536x512]
    ushort_t* WsT_hi  = (ushort_t*)(ws + (size_t)36044800);  // [1536x512]
    ushort_t* WsT_lo  = (ushort_t*)(ws + (size_t)36438016);  // [1536x512]
    ushort_t* WpT_hi  = (ushort_t*)(ws + (size_t)36831232);  // [512x1024]
    ushort_t* WpT_lo  = (ushort_t*)(ws + (size_t)37093376);  // [512x1024]

    prep_kernel<<<2561, 256, 0, stream>>>(x, ln_g, ln_b, xhi, xlo,
                                          qkv_d_w, WdT_hi,
                                          qkv_s_w, WsT_hi, WsT_lo,
                                          proj_s_w, proj_d_w, WpT_hi, WpT_lo,
                                          proj_s_b, proj_d_b, fw, biasc);

    gemm_bf16_mfma<0, 1><<<dim3(64, 12), 256, 0, stream>>>(xhi, nullptr, WdT_hi, nullptr,
                                                           qkv_d_b, nullptr, qkvd_bf,
                                                           QKV_N, CDIM);
    gemm_bf16_mfma<1, 0><<<dim3(64, 12), 256, 0, stream>>>(xhi, xlo, WsT_hi, WsT_lo,
                                                           qkv_s_b, qkvs, nullptr,
                                                           QKV_N, CDIM);

    vt_skv_kernel<<<1280, 256, 0, stream>>>(qkvd_bf, vtg, qkvs, kvpart);
    attn_sout_kernel<<<2048, 256, 0, stream>>>(qkvd_bf, vtg, qkvs, kvpart, fw, athi, atlo);

    gemm_proj<<<dim3(128, 4), 256, 0, stream>>>(athi, atlo, WpT_hi, WpT_lo,
                                                biasc, (float*)d_out);
}